// Round 9
// baseline (1455.643 us; speedup 1.0000x reference)
//
#include <hip/hip_runtime.h>

namespace {

constexpr int T_LEN = 2048;
constexpr int B_TOT = 2048;
constexpr int H1 = 36;
constexpr int NB = 4;        // batches per block (MFMA cols 0..3 used)
constexpr int BLOCK = 256;   // 3 A-waves + 1 L2 wave
constexpr int RS = 72;       // h row stride in halves: 144B (16B-aligned, 36 dwords -> 2-way banks = free)

typedef _Float16 f16x8 __attribute__((ext_vector_type(8)));
typedef _Float16 h16x2 __attribute__((ext_vector_type(2)));
typedef float f32x4 __attribute__((ext_vector_type(4)));

__device__ __forceinline__ float fdot2(float wb, float hb, float acc) {
#if __has_builtin(__builtin_amdgcn_fdot2)
  return __builtin_amdgcn_fdot2(__builtin_bit_cast(h16x2, wb),
                                __builtin_bit_cast(h16x2, hb), acc, false);
#else
  float d;
  asm("v_dot2_f32_f16 %0, %1, %2, %3" : "=v"(d) : "v"(wb), "v"(hb), "0"(acc));
  return d;
#endif
}
__device__ __forceinline__ float pack2h(float a, float b) {
  h16x2 t = {(_Float16)a, (_Float16)b};
  return __builtin_bit_cast(float, t);
}
__device__ __forceinline__ float pkmax0(float v, float z) {  // packed relu on 2 halves
  float d;
  asm("v_pk_max_f16 %0, %1, %2" : "=v"(d) : "v"(v), "v"(z));
  return d;
}
template <int PAT>
__device__ __forceinline__ float swzf(float v) {  // quad broadcast
  return __builtin_bit_cast(
      float, __builtin_amdgcn_ds_swizzle(__builtin_bit_cast(int, v), PAT));
}
__device__ __forceinline__ float fexp2(float x) { return __builtin_amdgcn_exp2f(x); }
__device__ __forceinline__ float frcp(float x) { return __builtin_amdgcn_rcpf(x); }
__device__ __forceinline__ float sigm(float x) { return frcp(1.f + fexp2(x * -1.44269504f)); }
__device__ __forceinline__ float tanh_fast(float x) {
  return fmaf(2.f, frcp(1.f + fexp2(x * -2.88539008f)), -1.f);  // 2*sigm(2x)-1
}

__global__ __launch_bounds__(BLOCK) void lstm2_kernel(
    const float* __restrict__ x, const float* __restrict__ Wih1,
    const float* __restrict__ Whh1, const float* __restrict__ bih1,
    const float* __restrict__ bhh1, const float* __restrict__ Wih2,
    const float* __restrict__ Whh2, const float* __restrict__ bih2,
    const float* __restrict__ bhh2, float* __restrict__ out)
{
  // Double-buffered h1 (fp16, B-operand layout [row=batch][k=unit], k>=36 zero).
  // Rows 4..15 exist only so B-frag reads by lanes m>=4 stay in-bounds; they are
  // zeroed once and never written -> MFMA cols 4..15 accumulate garbage*0.
  __shared__ __align__(16) _Float16 lds[2][16][RS];

  const int tid = threadIdx.x;
  const int wid = tid >> 6;
  const int lane = tid & 63;
  const int g0 = blockIdx.x * NB;
  const bool isA = wid < 3;

  for (int i = tid; i < 2 * 16 * RS; i += BLOCK) ((_Float16*)lds)[i] = (_Float16)0.f;
  __syncthreads();

  const int m = lane & 15;   // A/B row&col index; batch for m<NB
  const int q = lane >> 4;   // k-group / C row-group
  // A-wave wid: tiles tt = wid*3+j (j=0..2), units 4tt..4tt+3 (12 units/wave).
  f16x8 A0[3] = {}, A1[3] = {};
  float wxc[3][4] = {}, bxc[3][4] = {};
  float c1[3] = {0.f, 0.f, 0.f};
  const float* xc = nullptr;
  if (isA) {
#pragma unroll
    for (int j = 0; j < 3; ++j) {
      const int u0 = 4 * (wid * 3 + j);
      const int ra = (m & 3) * H1 + (u0 + (m >> 2));  // A row' m = uloc*4+g
#pragma unroll
      for (int jj = 0; jj < 8; ++jj) {
        A0[j][jj] = (_Float16)Whh1[ra * H1 + q * 8 + jj];  // k<=31
        const int k1 = 32 + q * 8 + jj;
        A1[j][jj] = (k1 < H1) ? (_Float16)Whh1[ra * H1 + k1] : (_Float16)0.f;
      }
#pragma unroll
      for (int r = 0; r < 4; ++r) {  // C rows: mrow=q*4+r -> unit u0+q, gate r
        const int rc = r * H1 + (u0 + q);
        wxc[j][r] = Wih1[rc];
        bxc[j][r] = bih1[rc] + bhh1[rc];
      }
    }
    xc = x + (size_t)(g0 + (m < NB ? m : NB - 1)) * T_LEN;  // clamp: lanes m>=NB dummy
  }

  // L2 wave: lanes 0..15, lane = batch*4 + gate.
  const int lb = lane >> 2, lg = lane & 3;
  float w2[18];
  float whg = 0.f, b2 = 0.f, c2 = 0.f, h2 = 0.f, zero = 0.f;
  float* outp = nullptr;
#pragma unroll
  for (int k = 0; k < 18; ++k) w2[k] = 0.f;
  if (!isA && lane < 16) {
    const float* wr = Wih2 + lg * H1;
#pragma unroll
    for (int k = 0; k < 18; ++k) w2[k] = pack2h(wr[2 * k], wr[2 * k + 1]);
    whg = Whh2[lg];
    b2 = bih2[lg] + bhh2[lg];
    outp = out + (size_t)(g0 + lb) * T_LEN;
  }

  float4 qx = make_float4(0.f, 0.f, 0.f, 0.f);
  if (isA) qx = *(const float4*)xc;
  float4 ov = make_float4(0.f, 0.f, 0.f, 0.f);

  // Step i: reads h_{i-1} from buf[(i+1)&1], writes h_i to buf[i&1].
  // L2 at step i computes out[i-1] from the same h_{i-1}.
  auto step = [&](int i, float xv, int s) {
    const int ib = (s + 1) & 1;
    const int wb = s & 1;
    if (isA) {
      const f16x8 B0 = *(const f16x8*)&lds[ib][m][q * 8];       // k=q*8..q*8+7
      const f16x8 B1 = *(const f16x8*)&lds[ib][m][32 + q * 8];  // k=32.. (zero-padded)
#pragma unroll
      for (int j = 0; j < 3; ++j) {
        f32x4 cc;
#pragma unroll
        for (int r = 0; r < 4; ++r) cc[r] = fmaf(xv, wxc[j][r], bxc[j][r]);
        cc = __builtin_amdgcn_mfma_f32_16x16x32_f16(A0[j], B0, cc, 0, 0, 0);
        cc = __builtin_amdgcn_mfma_f32_16x16x32_f16(A1[j], B1, cc, 0, 0, 0);
        const float I = sigm(cc[0]), F = sigm(cc[1]);
        const float G = tanh_fast(cc[2]), O = sigm(cc[3]);
        c1[j] = fmaf(F, c1[j], I * G);
        const float h = O * tanh_fast(c1[j]);
        if (m < NB) lds[wb][m][4 * (wid * 3 + j) + q] = (_Float16)h;
      }
    } else if (i > 0 && lane < 16) {
      const char* rp = (const char*)&lds[ib][lb][0];  // h_{i-1}, batch lb
      const float4 r0 = *(const float4*)rp;
      const float4 r1 = *(const float4*)(rp + 16);
      const float4 r2 = *(const float4*)(rp + 32);
      const float4 r3 = *(const float4*)(rp + 48);
      const float2 r4 = *(const float2*)(rp + 64);
      float f[18] = {r0.x, r0.y, r0.z, r0.w, r1.x, r1.y, r1.z, r1.w,
                     r2.x, r2.y, r2.z, r2.w, r3.x, r3.y, r3.z, r3.w,
                     r4.x, r4.y};
      float aE = 0.f, aO = 0.f;
#pragma unroll
      for (int k = 0; k < 18; k += 2) aE = fdot2(w2[k], pkmax0(f[k], zero), aE);
#pragma unroll
      for (int k = 1; k < 18; k += 2) aO = fdot2(w2[k], pkmax0(f[k], zero), aO);
      const float pre = (aE + aO) + fmaf(h2, whg, b2);  // this lane's gate lg
      const float pI = swzf<0x8000 | 0x00>(pre);
      const float pF = swzf<0x8000 | 0x55>(pre);
      const float pG = swzf<0x8000 | 0xAA>(pre);
      const float pO = swzf<0x8000 | 0xFF>(pre);
      c2 = fmaf(sigm(pF), c2, sigm(pI) * tanh_fast(pG));
      h2 = sigm(pO) * tanh_fast(c2);  // = out[i-1]
      if (s == 1) ov.x = h2;
      else if (s == 2) ov.y = h2;
      else if (s == 3) ov.z = h2;
      else {
        ov.w = h2;
        if (lg == 0) *(float4*)(outp + (i - 4)) = ov;  // out[i-4..i-1]
      }
    }
    __syncthreads();
  };

  for (int i0 = 0; i0 < T_LEN; i0 += 4) {
    float4 qn = qx;
    if (isA) {
      const int tn = (i0 + 4 < T_LEN) ? (i0 + 4) : (T_LEN - 4);
      qn = *(const float4*)(xc + tn);
    }
    step(i0 + 0, qx.x, 0);
    step(i0 + 1, qx.y, 1);
    step(i0 + 2, qx.z, 2);
    step(i0 + 3, qx.w, 3);
    qx = qn;
  }
  // Flush: A computes discarded h_2048; L2 emits out[2047], stores last quad.
  step(T_LEN, qx.x, 0);
}

}  // namespace

extern "C" void kernel_launch(void* const* d_in, const int* in_sizes, int n_in,
                              void* d_out, int out_size, void* d_ws, size_t ws_size,
                              hipStream_t stream) {
  const float* x    = (const float*)d_in[0];
  const float* Wih1 = (const float*)d_in[1];
  const float* Whh1 = (const float*)d_in[2];
  const float* bih1 = (const float*)d_in[3];
  const float* bhh1 = (const float*)d_in[4];
  const float* Wih2 = (const float*)d_in[5];
  const float* Whh2 = (const float*)d_in[6];
  const float* bih2 = (const float*)d_in[7];
  const float* bhh2 = (const float*)d_in[8];
  float* out = (float*)d_out;

  dim3 grid(B_TOT / NB);  // 512 blocks -> 2 per CU: all CUs busy, convoy overlap
  dim3 block(BLOCK);      // 3 A-waves + 1 L2 wave
  hipLaunchKernelGGL(lstm2_kernel, grid, block, 0, stream,
                     x, Wih1, Whh1, bih1, bhh1, Wih2, Whh2, bih2, bhh2, out);
}

// Round 10
// 979.535 us; speedup vs baseline: 1.4861x; 1.4861x over previous
//
#include <hip/hip_runtime.h>

namespace {

constexpr int T_LEN = 2048;
constexpr int B_TOT = 2048;
constexpr int H1 = 36;
constexpr int NB = 8;        // live batches per block (B cols 0..7; 8..15 bounded garbage)
constexpr int BLOCK = 640;   // 9 A-waves (1 M-tile each) + 1 L2 wave
constexpr int RS = 72;       // h row stride in halves = 36 dwords -> 2-way banks (free)

typedef _Float16 f16x8 __attribute__((ext_vector_type(8)));
typedef _Float16 h16x2 __attribute__((ext_vector_type(2)));
typedef float f32x4 __attribute__((ext_vector_type(4)));

__device__ __forceinline__ float fdot2(float wb, float hb, float acc) {
#if __has_builtin(__builtin_amdgcn_fdot2)
  return __builtin_amdgcn_fdot2(__builtin_bit_cast(h16x2, wb),
                                __builtin_bit_cast(h16x2, hb), acc, false);
#else
  float d;
  asm("v_dot2_f32_f16 %0, %1, %2, %3" : "=v"(d) : "v"(wb), "v"(hb), "0"(acc));
  return d;
#endif
}
__device__ __forceinline__ float pack2h(float a, float b) {
  h16x2 t = {(_Float16)a, (_Float16)b};
  return __builtin_bit_cast(float, t);
}
__device__ __forceinline__ float pkmax0(float v, float z) {  // packed fp16 relu
  float d;
  asm("v_pk_max_f16 %0, %1, %2" : "=v"(d) : "v"(v), "v"(z));
  return d;
}
template <int PAT>
__device__ __forceinline__ float swzf(float v) {  // quad broadcast
  return __builtin_bit_cast(
      float, __builtin_amdgcn_ds_swizzle(__builtin_bit_cast(int, v), PAT));
}
__device__ __forceinline__ float fexp2(float x) { return __builtin_amdgcn_exp2f(x); }
__device__ __forceinline__ float frcp(float x) { return __builtin_amdgcn_rcpf(x); }
__device__ __forceinline__ float sigm(float x) { return frcp(1.f + fexp2(x * -1.44269504f)); }
__device__ __forceinline__ float tanh_fast(float x) {
  return fmaf(2.f, frcp(1.f + fexp2(x * -2.88539008f)), -1.f);  // 2*sigm(2x)-1
}

__global__ __launch_bounds__(BLOCK) void lstm2_kernel(
    const float* __restrict__ x, const float* __restrict__ Wih1,
    const float* __restrict__ Whh1, const float* __restrict__ bih1,
    const float* __restrict__ bhh1, const float* __restrict__ Wih2,
    const float* __restrict__ Whh2, const float* __restrict__ bih2,
    const float* __restrict__ bhh2, float* __restrict__ out)
{
  // Double-buffered h1 (fp16, B-layout [row=batch][k=unit]); k>=36 and rows>=NB
  // are zero/bounded-garbage. RS=72 halves: 16B-aligned rows, 2-way banking.
  __shared__ __align__(16) _Float16 lds[2][16][RS];

  const int tid = threadIdx.x;
  const int wid = tid >> 6;
  const int lane = tid & 63;
  const int g0 = blockIdx.x * NB;
  const bool isA = wid < 9;

  for (int i = tid; i < 2 * 16 * RS; i += BLOCK) ((_Float16*)lds)[i] = (_Float16)0.f;
  __syncthreads();

  const int m = lane & 15;   // A row idx / B,C batch col (live m<NB)
  const int q = lane >> 4;   // k-group / C row-group
  f16x8 A0 = {}, A1 = {};
  float wxc[4] = {0, 0, 0, 0}, bxc[4] = {0, 0, 0, 0};
  float c1 = 0.f;
  const float* xc = nullptr;
  if (isA) {
    const int u0 = wid * 4;                         // this wave's unit group
    const int ra = (m & 3) * H1 + (u0 + (m >> 2));  // A row' m = uloc*4+g
#pragma unroll
    for (int j = 0; j < 8; ++j) {
      A0[j] = (_Float16)Whh1[ra * H1 + q * 8 + j];  // k<=31
      const int k1 = 32 + q * 8 + j;
      A1[j] = (k1 < H1) ? (_Float16)Whh1[ra * H1 + k1] : (_Float16)0.f;
    }
#pragma unroll
    for (int r = 0; r < 4; ++r) {  // C rows: mrow=q*4+r -> unit u0+q, gate r
      const int rc = r * H1 + (u0 + q);
      wxc[r] = Wih1[rc];
      bxc[r] = bih1[rc] + bhh1[rc];
    }
    xc = x + (size_t)(g0 + (m < NB ? m : NB - 1)) * T_LEN;  // clamp dummy lanes
  }

  // L2 wave: lane = batch*4 + gate (lanes with lb>=NB compute bounded garbage).
  const int lb = lane >> 2, lg = lane & 3;
  float w2[18];
  float whg = 0.f, b2 = 0.f, c2 = 0.f, h2 = 0.f, zero = 0.f;
  float* outp = nullptr;
#pragma unroll
  for (int k = 0; k < 18; ++k) w2[k] = 0.f;
  if (!isA) {
    const float* wr = Wih2 + lg * H1;
#pragma unroll
    for (int k = 0; k < 18; ++k) w2[k] = pack2h(wr[2 * k], wr[2 * k + 1]);
    whg = Whh2[lg];
    b2 = bih2[lg] + bhh2[lg];
    outp = out + (size_t)(g0 + (lb < NB ? lb : NB - 1)) * T_LEN;
  }

  float4 qx = make_float4(0.f, 0.f, 0.f, 0.f);
  if (isA) qx = *(const float4*)xc;
  float4 ov = make_float4(0.f, 0.f, 0.f, 0.f);

  // Step i: A reads h_{i-1} from buf[(i+1)&1], writes h_i to buf[i&1];
  // L2 computes out[i-1] from the same h_{i-1}. One barrier per step.
  auto step = [&](int i, float xv, int s) {
    const int ib = (s + 1) & 1;
    const int wb = s & 1;
    if (isA) {
      const f16x8 B0 = *(const f16x8*)&lds[ib][m][q * 8];       // k=q*8..+7
      const f16x8 B1 = *(const f16x8*)&lds[ib][m][32 + q * 8];  // zero-padded
      f32x4 cc;
#pragma unroll
      for (int r = 0; r < 4; ++r) cc[r] = fmaf(xv, wxc[r], bxc[r]);
      cc = __builtin_amdgcn_mfma_f32_16x16x32_f16(A0, B0, cc, 0, 0, 0);
      cc = __builtin_amdgcn_mfma_f32_16x16x32_f16(A1, B1, cc, 0, 0, 0);
      const float I = sigm(cc[0]), F = sigm(cc[1]);
      const float G = tanh_fast(cc[2]), O = sigm(cc[3]);
      c1 = fmaf(F, c1, I * G);
      const float h = O * tanh_fast(c1);
      lds[wb][m][(wid << 2) + q] = (_Float16)h;  // rows m>=NB: bounded garbage
    } else if (i > 0) {
      const char* rp = (const char*)&lds[ib][lb][0];  // h_{i-1}, batch lb
      const float4 r0 = *(const float4*)rp;
      const float4 r1 = *(const float4*)(rp + 16);
      const float4 r2 = *(const float4*)(rp + 32);
      const float4 r3 = *(const float4*)(rp + 48);
      const float2 r4 = *(const float2*)(rp + 64);
      const float f[18] = {r0.x, r0.y, r0.z, r0.w, r1.x, r1.y, r1.z, r1.w,
                           r2.x, r2.y, r2.z, r2.w, r3.x, r3.y, r3.z, r3.w,
                           r4.x, r4.y};
      float aE = 0.f, aO = 0.f;
#pragma unroll
      for (int k = 0; k < 18; k += 2) aE = fdot2(w2[k], pkmax0(f[k], zero), aE);
#pragma unroll
      for (int k = 1; k < 18; k += 2) aO = fdot2(w2[k], pkmax0(f[k], zero), aO);
      const float pre = (aE + aO) + fmaf(h2, whg, b2);  // this lane's gate lg
      const float pI = swzf<0x8000 | 0x00>(pre);
      const float pF = swzf<0x8000 | 0x55>(pre);
      const float pG = swzf<0x8000 | 0xAA>(pre);
      const float pO = swzf<0x8000 | 0xFF>(pre);
      c2 = fmaf(sigm(pF), c2, sigm(pI) * tanh_fast(pG));
      h2 = sigm(pO) * tanh_fast(c2);  // = out[i-1], replicated in quad
      if (s == 1) ov.x = h2;
      else if (s == 2) ov.y = h2;
      else if (s == 3) ov.z = h2;
      else {
        ov.w = h2;
        if (lg == 0 && lb < NB) *(float4*)(outp + (i - 4)) = ov;  // out[i-4..i-1]
      }
    }
    __syncthreads();
  };

  for (int i0 = 0; i0 < T_LEN; i0 += 4) {
    float4 qn = qx;
    if (isA) {
      const int tn = (i0 + 4 < T_LEN) ? (i0 + 4) : (T_LEN - 4);
      qn = *(const float4*)(xc + tn);
    }
    step(i0 + 0, qx.x, 0);
    step(i0 + 1, qx.y, 1);
    step(i0 + 2, qx.z, 2);
    step(i0 + 3, qx.w, 3);
    qx = qn;
  }
  // Flush: A computes discarded h_2048; L2 emits out[2047] and stores last quad.
  step(T_LEN, qx.x, 0);
}

}  // namespace

extern "C" void kernel_launch(void* const* d_in, const int* in_sizes, int n_in,
                              void* d_out, int out_size, void* d_ws, size_t ws_size,
                              hipStream_t stream) {
  const float* x    = (const float*)d_in[0];
  const float* Wih1 = (const float*)d_in[1];
  const float* Whh1 = (const float*)d_in[2];
  const float* bih1 = (const float*)d_in[3];
  const float* bhh1 = (const float*)d_in[4];
  const float* Wih2 = (const float*)d_in[5];
  const float* Whh2 = (const float*)d_in[6];
  const float* bih2 = (const float*)d_in[7];
  const float* bhh2 = (const float*)d_in[8];
  float* out = (float*)d_out;

  dim3 grid(B_TOT / NB);  // 256 blocks -> exactly 1 per CU (no placement contention)
  dim3 block(BLOCK);      // 9 MFMA waves + 1 L2 wave
  hipLaunchKernelGGL(lstm2_kernel, grid, block, 0, stream,
                     x, Wih1, Whh1, bih1, bhh1, Wih2, Whh2, bih2, bhh2, out);
}